// Round 11
// baseline (141.768 us; speedup 1.0000x reference)
//
#include <hip/hip_runtime.h>

#define F_IN 128
#define F_H 64
#define F_OUT 16
#define RB 128           // nodes per bucket
#define RB_SHIFT 7       // bucket = dst >> 7
#define DBINS 64         // degree bins for bucket-local degree ranking
#define CAP 3072         // global bucket capacity (mean 2047, sigma 45)
#define LDSCAP 2816      // LDS sorted-edge capacity (mean + 17 sigma)

typedef unsigned long long u64;
typedef unsigned int u32;

__device__ __forceinline__ u32 pack2bf16(float a, float b) {
    u32 ua = (__float_as_uint(a) + 0x8000u) >> 16;
    u32 ub = (__float_as_uint(b) + 0x8000u) & 0xFFFF0000u;
    return ua | ub;
}

// ---------------------------------------------------------------------------
// GEMM1: h1[N,64](bf16 packed in u32 pairs) = x[N,128] @ W1[128,64]
// ---------------------------------------------------------------------------
__global__ __launch_bounds__(256) void gemm1_kernel(
    const float* __restrict__ x, const float* __restrict__ W,
    u32* __restrict__ h1b, int N) {
    __shared__ float Wlds[64 * 64];
    __shared__ float Xlds[64][69];

    const int tid = threadIdx.x;
    const int n0 = blockIdx.x * 64;
    const int tf = tid & 15;
    const int tn = tid >> 4;

    float acc[4][4] = {{0.f, 0.f, 0.f, 0.f}, {0.f, 0.f, 0.f, 0.f},
                       {0.f, 0.f, 0.f, 0.f}, {0.f, 0.f, 0.f, 0.f}};

    for (int p = 0; p < 2; ++p) {
        for (int i = tid; i < 1024; i += 256) {
            const int kk = i >> 4, c4 = i & 15;
            float4 v = *(const float4*)(W + (size_t)(64 * p + kk) * 64 + 4 * c4);
            *(float4*)(&Wlds[kk * 64 + 4 * c4]) = v;
        }
        for (int i = tid; i < 1024; i += 256) {
            const int row = i >> 4, c4 = i & 15;
            int n = n0 + row;
            if (n >= N) n = N - 1;
            float4 v = *(const float4*)(x + (size_t)n * F_IN + 64 * p + 4 * c4);
            Xlds[row][4 * c4 + 0] = v.x;
            Xlds[row][4 * c4 + 1] = v.y;
            Xlds[row][4 * c4 + 2] = v.z;
            Xlds[row][4 * c4 + 3] = v.w;
        }
        __syncthreads();

        #pragma unroll 4
        for (int kk = 0; kk < 64; ++kk) {
            float4 w4 = *(const float4*)(&Wlds[kk * 64 + 4 * tf]);
            float xv[4];
            #pragma unroll
            for (int i2 = 0; i2 < 4; ++i2) xv[i2] = Xlds[4 * tn + i2][kk];
            #pragma unroll
            for (int i2 = 0; i2 < 4; ++i2) {
                acc[i2][0] += xv[i2] * w4.x;
                acc[i2][1] += xv[i2] * w4.y;
                acc[i2][2] += xv[i2] * w4.z;
                acc[i2][3] += xv[i2] * w4.w;
            }
        }
        __syncthreads();
    }

    #pragma unroll
    for (int i2 = 0; i2 < 4; ++i2) {
        const int n = n0 + 4 * tn + i2;
        if (n < N) {
            uint2 o = make_uint2(pack2bf16(acc[i2][0], acc[i2][1]),
                                 pack2bf16(acc[i2][2], acc[i2][3]));
            *(uint2*)(h1b + (size_t)n * 32 + tf * 2) = o;
        }
    }
}

// ---------------------------------------------------------------------------
// fill: block-local counting sort into CAP-strided bucket-grouped edata1
// entry: [63:32]=weight f32 bits, [26:20]=dst&127, [19:0]=src
// gcur[b] (zeroed before) ends as the bucket's edge count.
// ---------------------------------------------------------------------------
__global__ __launch_bounds__(1024) void fill_kernel(
    const int* __restrict__ src, const int* __restrict__ dst,
    const float* __restrict__ ew, int* __restrict__ gcur,
    u64* __restrict__ edata, int E, int nbuck) {
    __shared__ int cnt[800];
    __shared__ int base[800];
    int chunk = (E + gridDim.x - 1) / gridDim.x;
    chunk = (chunk + 3) & ~3;
    const int e0 = blockIdx.x * chunk;
    const int e1 = min(e0 + chunk, E);

    for (int i = threadIdx.x; i < nbuck; i += 1024) cnt[i] = 0;
    __syncthreads();

    int e = e0 + threadIdx.x * 4;
    for (; e + 3 < e1; e += 4096) {
        const int4 d4 = *(const int4*)(dst + e);
        atomicAdd(&cnt[d4.x >> RB_SHIFT], 1);
        atomicAdd(&cnt[d4.y >> RB_SHIFT], 1);
        atomicAdd(&cnt[d4.z >> RB_SHIFT], 1);
        atomicAdd(&cnt[d4.w >> RB_SHIFT], 1);
    }
    for (; e < e1; ++e) atomicAdd(&cnt[dst[e] >> RB_SHIFT], 1);
    __syncthreads();

    for (int i = threadIdx.x; i < nbuck; i += 1024) {
        const int c = cnt[i];
        base[i] = i * CAP + (c ? atomicAdd(&gcur[i], c) : 0);
        cnt[i] = 0;
    }
    __syncthreads();

    e = e0 + threadIdx.x * 4;
    for (; e + 3 < e1; e += 4096) {
        const int4 d4 = *(const int4*)(dst + e);
        const int4 s4 = *(const int4*)(src + e);
        const float4 w4 = *(const float4*)(ew + e);
        {
            const int b = d4.x >> RB_SHIFT;
            const int p = atomicAdd(&cnt[b], 1);
            edata[(size_t)base[b] + p] = ((u64)__float_as_uint(w4.x) << 32) |
                (u32)s4.x | ((u32)(d4.x & (RB - 1)) << 20);
        }
        {
            const int b = d4.y >> RB_SHIFT;
            const int p = atomicAdd(&cnt[b], 1);
            edata[(size_t)base[b] + p] = ((u64)__float_as_uint(w4.y) << 32) |
                (u32)s4.y | ((u32)(d4.y & (RB - 1)) << 20);
        }
        {
            const int b = d4.z >> RB_SHIFT;
            const int p = atomicAdd(&cnt[b], 1);
            edata[(size_t)base[b] + p] = ((u64)__float_as_uint(w4.z) << 32) |
                (u32)s4.z | ((u32)(d4.z & (RB - 1)) << 20);
        }
        {
            const int b = d4.w >> RB_SHIFT;
            const int p = atomicAdd(&cnt[b], 1);
            edata[(size_t)base[b] + p] = ((u64)__float_as_uint(w4.w) << 32) |
                (u32)s4.w | ((u32)(d4.w & (RB - 1)) << 20);
        }
    }
    for (; e < e1; ++e) {
        const int d = dst[e];
        const int b = d >> RB_SHIFT;
        const int p = atomicAdd(&cnt[b], 1);
        edata[(size_t)base[b] + p] = ((u64)__float_as_uint(ew[e]) << 32) |
            (u32)src[e] | ((u32)(d & (RB - 1)) << 20);
    }
}

// ---------------------------------------------------------------------------
// aggL1: one 512-thread block per bucket.
//  1) counting-sort edges by local dst into LDS (esh); degree-rank nodes
//  2) write sorted edges back IN PLACE (coalesced) + rowbeg/rowend/perm
//  3) 64 groups x 8 lanes; group g handles ranks {g, 127-g}; uint4 bf16
//     gathers (8 feats/lane), register acc; relu + W2 mini-GEMM -> h2b
// ---------------------------------------------------------------------------
__global__ __launch_bounds__(512) void aggL1_kernel(
    const u32* __restrict__ h1b, u64* __restrict__ edata,
    const int* __restrict__ gcnt, const float* __restrict__ b1,
    const float* __restrict__ W2, u32* __restrict__ h2b,
    int* __restrict__ rowbeg, int* __restrict__ rowend,
    int* __restrict__ perm, int N) {
    __shared__ u64 esh[LDSCAP];          // 22.5 KB sorted edges
    __shared__ float2 w2p[64][8];        // w2p[k][l] = (W2[k][2l], W2[k][2l+1])
    __shared__ int cnt[RB];
    __shared__ int pref[RB];             // inclusive prefix
    __shared__ int cur[RB];
    __shared__ int dbin[DBINS];
    __shared__ int dcur[DBINS];
    __shared__ int nodeOrder[RB];

    const int tid = threadIdx.x;
    const int b = blockIdx.x;
    const size_t s0 = (size_t)b * CAP;
    const int ecount = min(gcnt[b], LDSCAP);

    {   // load W2 as float2 pairs: 512 entries, one per thread
        const int k = tid >> 3, l = tid & 7;
        w2p[k][l] = make_float2(W2[k * 16 + 2 * l], W2[k * 16 + 2 * l + 1]);
    }
    if (tid < RB) cnt[tid] = 0;
    if (tid < DBINS) dbin[tid] = 0;
    __syncthreads();

    // pass 1: per-node counts
    for (int i = tid; i < ecount; i += 512) {
        const int d = ((u32)edata[s0 + i] >> 20) & (RB - 1);
        atomicAdd(&cnt[d], 1);
    }
    __syncthreads();
    if (tid < RB) pref[tid] = cnt[tid];
    __syncthreads();
    for (int o = 1; o < RB; o <<= 1) {
        int v = 0;
        if (tid < RB && tid >= o) v = pref[tid - o];
        __syncthreads();
        if (tid < RB) pref[tid] += v;
        __syncthreads();
    }
    if (tid < RB) {
        const int ex = pref[tid] - cnt[tid];
        cur[tid] = ex;
        const int gn = b * RB + tid;
        rowbeg[gn] = (int)s0 + ex;                      // global run bounds
        rowend[gn] = (int)s0 + pref[tid];
        atomicAdd(&dbin[min(cnt[tid], DBINS - 1)], 1);  // degree histogram
    }
    __syncthreads();
    if (tid < DBINS) dcur[tid] = dbin[tid];
    __syncthreads();
    for (int o = 1; o < DBINS; o <<= 1) {
        int v = 0;
        if (tid < DBINS && tid >= o) v = dcur[tid - o];
        __syncthreads();
        if (tid < DBINS) dcur[tid] += v;
        __syncthreads();
    }
    if (tid < DBINS) dcur[tid] -= dbin[tid];            // exclusive
    __syncthreads();
    if (tid < RB) {
        const int r = atomicAdd(&dcur[min(cnt[tid], DBINS - 1)], 1);
        nodeOrder[r] = tid;
        perm[b * RB + r] = b * RB + tid;                // degree-ranked node id
    }
    // pass 2: scatter edges into LDS in node-sorted order
    for (int i = tid; i < ecount; i += 512) {
        const u64 ed = edata[s0 + i];
        const int d = ((u32)ed >> 20) & (RB - 1);
        const int p = atomicAdd(&cur[d], 1);
        esh[p] = ed;
    }
    __syncthreads();

    // write sorted edges back in place (coalesced; block owns this slice)
    for (int i = tid; i < ecount; i += 512) edata[s0 + i] = esh[i];

    // aggregation: group g (8 lanes) handles degree ranks {g, 127-g}
    const int g = tid >> 3;
    const int l = tid & 7;               // feats 8l .. 8l+7
    const int gb8 = (tid & 63) & 56;     // wave-local 8-lane group base
    const int ranks[2] = {g, 127 - g};

    #pragma unroll
    for (int t = 0; t < 2; ++t) {
        const int ln = nodeOrder[ranks[t]];
        const int gn = b * RB + ln;
        const int end = pref[ln];
        int i = end - cnt[ln];

        float acc[8];
        {
            const float4 ba = *(const float4*)(b1 + 8 * l);
            const float4 bb = *(const float4*)(b1 + 8 * l + 4);
            acc[0] = ba.x; acc[1] = ba.y; acc[2] = ba.z; acc[3] = ba.w;
            acc[4] = bb.x; acc[5] = bb.y; acc[6] = bb.z; acc[7] = bb.w;
        }
        for (; i + 4 <= end; i += 4) {
            u64 e[4];
            uint4 v[4];
            #pragma unroll
            for (int j = 0; j < 4; ++j) e[j] = esh[i + j];
            #pragma unroll
            for (int j = 0; j < 4; ++j)
                v[j] = *(const uint4*)(h1b + (size_t)((u32)e[j] & 0xFFFFF) * 32 + l * 4);
            #pragma unroll
            for (int j = 0; j < 4; ++j) {
                const float w = __uint_as_float((u32)(e[j] >> 32));
                acc[0] += __uint_as_float(v[j].x << 16) * w;
                acc[1] += __uint_as_float(v[j].x & 0xFFFF0000u) * w;
                acc[2] += __uint_as_float(v[j].y << 16) * w;
                acc[3] += __uint_as_float(v[j].y & 0xFFFF0000u) * w;
                acc[4] += __uint_as_float(v[j].z << 16) * w;
                acc[5] += __uint_as_float(v[j].z & 0xFFFF0000u) * w;
                acc[6] += __uint_as_float(v[j].w << 16) * w;
                acc[7] += __uint_as_float(v[j].w & 0xFFFF0000u) * w;
            }
        }
        for (; i < end; ++i) {
            const u64 e0 = esh[i];
            const float w0 = __uint_as_float((u32)(e0 >> 32));
            const uint4 v0 = *(const uint4*)(h1b + (size_t)((u32)e0 & 0xFFFFF) * 32 + l * 4);
            acc[0] += __uint_as_float(v0.x << 16) * w0;
            acc[1] += __uint_as_float(v0.x & 0xFFFF0000u) * w0;
            acc[2] += __uint_as_float(v0.y << 16) * w0;
            acc[3] += __uint_as_float(v0.y & 0xFFFF0000u) * w0;
            acc[4] += __uint_as_float(v0.z << 16) * w0;
            acc[5] += __uint_as_float(v0.z & 0xFFFF0000u) * w0;
            acc[6] += __uint_as_float(v0.w << 16) * w0;
            acc[7] += __uint_as_float(v0.w & 0xFFFF0000u) * w0;
        }

        // relu
        float racc[8];
        #pragma unroll
        for (int m = 0; m < 8; ++m) racc[m] = fmaxf(acc[m], 0.f);

        // mini-GEMM: lane l computes cols 2l, 2l+1
        float o0 = 0.f, o1 = 0.f;
        #pragma unroll
        for (int kb = 0; kb < 8; ++kb) {
            #pragma unroll
            for (int m = 0; m < 8; ++m) {
                const float r = __shfl(racc[m], gb8 + kb, 64);
                const float2 w = w2p[kb * 8 + m][l];
                o0 += r * w.x;
                o1 += r * w.y;
            }
        }
        if (gn < N) {
            h2b[(size_t)gn * 8 + l] = pack2bf16(o0, o1);
        }
    }
}

// ---------------------------------------------------------------------------
// aggL2: flat kernel, 4 lanes/node in degree-ranked perm order; reads the
// node-sorted edge runs directly from global (written back by aggL1);
// register acc, bf16 uint2 gathers from L2-resident h2b, unroll 8. No LDS.
// ---------------------------------------------------------------------------
__global__ __launch_bounds__(256) void aggL2_kernel(
    const u32* __restrict__ h2b, const u64* __restrict__ edata,
    const int* __restrict__ rowbeg, const int* __restrict__ rowend,
    const int* __restrict__ perm, const float* __restrict__ b2,
    float* __restrict__ out, int NP, int N) {
    const int tid = threadIdx.x;
    const int idx = (blockIdx.x * 256 + tid) >> 2;
    if (idx >= NP) return;
    const int n = perm[idx];
    const int lane = tid & 3;            // feats lane*4 .. lane*4+3

    int i = rowbeg[n];
    const int end = rowend[n];
    float4 acc = ((const float4*)b2)[lane];

    for (; i + 8 <= end; i += 8) {
        u64 e[8];
        uint2 v[8];
        #pragma unroll
        for (int j = 0; j < 8; ++j) e[j] = edata[i + j];
        #pragma unroll
        for (int j = 0; j < 8; ++j)
            v[j] = *(const uint2*)(h2b + (size_t)((u32)e[j] & 0xFFFFF) * 8 + lane * 2);
        #pragma unroll
        for (int j = 0; j < 8; ++j) {
            const float w = __uint_as_float((u32)(e[j] >> 32));
            acc.x += __uint_as_float(v[j].x << 16) * w;
            acc.y += __uint_as_float(v[j].x & 0xFFFF0000u) * w;
            acc.z += __uint_as_float(v[j].y << 16) * w;
            acc.w += __uint_as_float(v[j].y & 0xFFFF0000u) * w;
        }
    }
    if (i + 4 <= end) {
        u64 e[4];
        uint2 v[4];
        #pragma unroll
        for (int j = 0; j < 4; ++j) e[j] = edata[i + j];
        #pragma unroll
        for (int j = 0; j < 4; ++j)
            v[j] = *(const uint2*)(h2b + (size_t)((u32)e[j] & 0xFFFFF) * 8 + lane * 2);
        #pragma unroll
        for (int j = 0; j < 4; ++j) {
            const float w = __uint_as_float((u32)(e[j] >> 32));
            acc.x += __uint_as_float(v[j].x << 16) * w;
            acc.y += __uint_as_float(v[j].x & 0xFFFF0000u) * w;
            acc.z += __uint_as_float(v[j].y << 16) * w;
            acc.w += __uint_as_float(v[j].y & 0xFFFF0000u) * w;
        }
        i += 4;
    }
    for (; i < end; ++i) {
        const u64 e0 = edata[i];
        const float w0 = __uint_as_float((u32)(e0 >> 32));
        const uint2 v0 = *(const uint2*)(h2b + (size_t)((u32)e0 & 0xFFFFF) * 8 + lane * 2);
        acc.x += __uint_as_float(v0.x << 16) * w0;
        acc.y += __uint_as_float(v0.x & 0xFFFF0000u) * w0;
        acc.z += __uint_as_float(v0.y << 16) * w0;
        acc.w += __uint_as_float(v0.y & 0xFFFF0000u) * w0;
    }
    if (n < N) {
        *(float4*)(out + (size_t)n * F_OUT + lane * 4) = acc;
    }
}

extern "C" void kernel_launch(void* const* d_in, const int* in_sizes, int n_in,
                              void* d_out, int out_size, void* d_ws, size_t ws_size,
                              hipStream_t stream) {
    const float* x   = (const float*)d_in[0];
    const int*   src = (const int*)d_in[1];
    const int*   dst = (const int*)d_in[2];
    const float* ew  = (const float*)d_in[3];
    const float* W1  = (const float*)d_in[4];
    const float* b1  = (const float*)d_in[5];
    const float* W2  = (const float*)d_in[6];
    const float* b2  = (const float*)d_in[7];
    float* out = (float*)d_out;

    const int N = in_sizes[0] / F_IN;            // 100000
    const int E = in_sizes[1];                   // 1600000
    const int nbuck = (N + RB - 1) >> RB_SHIFT;  // 782
    const int NP = nbuck * RB;                   // 100096 padded nodes

    char* base = (char*)d_ws;
    auto align256 = [](size_t v) { return (v + 255) & ~(size_t)255; };
    size_t oH1   = 0;
    size_t oED1  = align256(oH1   + (size_t)N * 32 * 4);      // h1b bf16 12.8MB
    size_t oH2B  = align256(oED1  + (size_t)nbuck * CAP * 8); // edata1 19.2MB
    size_t oCUR  = align256(oH2B  + (size_t)N * 8 * 4);       // h2b bf16 3.2MB
    size_t oRB_  = align256(oCUR  + (size_t)nbuck * 4);
    size_t oRE_  = align256(oRB_  + (size_t)NP * 4);
    size_t oPERM = align256(oRE_  + (size_t)NP * 4);
    (void)ws_size;

    u32*   h1b    = (u32*)(base + oH1);
    u64*   edata1 = (u64*)(base + oED1);
    u32*   h2b    = (u32*)(base + oH2B);
    int*   gcur   = (int*)(base + oCUR);
    int*   rowbeg = (int*)(base + oRB_);
    int*   rowend = (int*)(base + oRE_);
    int*   perm   = (int*)(base + oPERM);

    // ---- preprocessing: CAP-strided bucket fill (counts end up in gcur)
    hipMemsetAsync(gcur, 0, (size_t)nbuck * 4, stream);
    fill_kernel<<<256, 1024, 0, stream>>>(src, dst, ew, gcur, edata1, E, nbuck);

    // ---- layer 1 transform
    gemm1_kernel<<<(N + 63) / 64, 256, 0, stream>>>(x, W1, h1b, N);
    // ---- layer-1 aggregate + relu + W2 (in-LDS sort, fused) -> h2b bf16;
    //      persists sorted edges + rowbeg/rowend/perm for aggL2
    aggL1_kernel<<<nbuck, 512, 0, stream>>>(h1b, edata1, gcur, b1, W2, h2b,
                                            rowbeg, rowend, perm, N);
    // ---- layer-2 aggregate + bias (flat, perm-ordered, no LDS, no sort)
    aggL2_kernel<<<(NP * 4 + 255) / 256, 256, 0, stream>>>(
        h2b, edata1, rowbeg, rowend, perm, b2, out, NP, N);
}

// Round 12
// 122.151 us; speedup vs baseline: 1.1606x; 1.1606x over previous
//
#include <hip/hip_runtime.h>

#define F_IN 128
#define F_H 64
#define F_OUT 16
#define RB 128           // nodes per bucket
#define RB_SHIFT 7       // bucket = dst >> 7
#define DBINS 64         // degree bins for bucket-local degree ranking
#define CAP 3072         // global bucket capacity (mean 2047, sigma 45)
#define LDSCAP 2816      // LDS sorted-edge capacity (mean + 17 sigma)

typedef unsigned long long u64;
typedef unsigned int u32;

__device__ __forceinline__ u32 pack2bf16(float a, float b) {
    u32 ua = (__float_as_uint(a) + 0x8000u) >> 16;
    u32 ub = (__float_as_uint(b) + 0x8000u) & 0xFFFF0000u;
    return ua | ub;
}

// ---------------------------------------------------------------------------
// GEMM1: h1[N,64](bf16 packed in u32 pairs) = x[N,128] @ W1[128,64]
// ---------------------------------------------------------------------------
__global__ __launch_bounds__(256) void gemm1_kernel(
    const float* __restrict__ x, const float* __restrict__ W,
    u32* __restrict__ h1b, int N) {
    __shared__ float Wlds[64 * 64];
    __shared__ float Xlds[64][69];

    const int tid = threadIdx.x;
    const int n0 = blockIdx.x * 64;
    const int tf = tid & 15;
    const int tn = tid >> 4;

    float acc[4][4] = {{0.f, 0.f, 0.f, 0.f}, {0.f, 0.f, 0.f, 0.f},
                       {0.f, 0.f, 0.f, 0.f}, {0.f, 0.f, 0.f, 0.f}};

    for (int p = 0; p < 2; ++p) {
        for (int i = tid; i < 1024; i += 256) {
            const int kk = i >> 4, c4 = i & 15;
            float4 v = *(const float4*)(W + (size_t)(64 * p + kk) * 64 + 4 * c4);
            *(float4*)(&Wlds[kk * 64 + 4 * c4]) = v;
        }
        for (int i = tid; i < 1024; i += 256) {
            const int row = i >> 4, c4 = i & 15;
            int n = n0 + row;
            if (n >= N) n = N - 1;
            float4 v = *(const float4*)(x + (size_t)n * F_IN + 64 * p + 4 * c4);
            Xlds[row][4 * c4 + 0] = v.x;
            Xlds[row][4 * c4 + 1] = v.y;
            Xlds[row][4 * c4 + 2] = v.z;
            Xlds[row][4 * c4 + 3] = v.w;
        }
        __syncthreads();

        #pragma unroll 4
        for (int kk = 0; kk < 64; ++kk) {
            float4 w4 = *(const float4*)(&Wlds[kk * 64 + 4 * tf]);
            float xv[4];
            #pragma unroll
            for (int i2 = 0; i2 < 4; ++i2) xv[i2] = Xlds[4 * tn + i2][kk];
            #pragma unroll
            for (int i2 = 0; i2 < 4; ++i2) {
                acc[i2][0] += xv[i2] * w4.x;
                acc[i2][1] += xv[i2] * w4.y;
                acc[i2][2] += xv[i2] * w4.z;
                acc[i2][3] += xv[i2] * w4.w;
            }
        }
        __syncthreads();
    }

    #pragma unroll
    for (int i2 = 0; i2 < 4; ++i2) {
        const int n = n0 + 4 * tn + i2;
        if (n < N) {
            uint2 o = make_uint2(pack2bf16(acc[i2][0], acc[i2][1]),
                                 pack2bf16(acc[i2][2], acc[i2][3]));
            *(uint2*)(h1b + (size_t)n * 32 + tf * 2) = o;
        }
    }
}

// ---------------------------------------------------------------------------
// fill: block-local counting sort into CAP-strided bucket-grouped edata1
// entry: [63:32]=weight f32 bits, [26:20]=dst&127, [19:0]=src
// gcur[b] (zeroed before) ends as the bucket's edge count.
// ---------------------------------------------------------------------------
__global__ __launch_bounds__(1024) void fill_kernel(
    const int* __restrict__ src, const int* __restrict__ dst,
    const float* __restrict__ ew, int* __restrict__ gcur,
    u64* __restrict__ edata, int E, int nbuck) {
    __shared__ int cnt[800];
    __shared__ int base[800];
    int chunk = (E + gridDim.x - 1) / gridDim.x;
    chunk = (chunk + 3) & ~3;
    const int e0 = blockIdx.x * chunk;
    const int e1 = min(e0 + chunk, E);

    for (int i = threadIdx.x; i < nbuck; i += 1024) cnt[i] = 0;
    __syncthreads();

    int e = e0 + threadIdx.x * 4;
    for (; e + 3 < e1; e += 4096) {
        const int4 d4 = *(const int4*)(dst + e);
        atomicAdd(&cnt[d4.x >> RB_SHIFT], 1);
        atomicAdd(&cnt[d4.y >> RB_SHIFT], 1);
        atomicAdd(&cnt[d4.z >> RB_SHIFT], 1);
        atomicAdd(&cnt[d4.w >> RB_SHIFT], 1);
    }
    for (; e < e1; ++e) atomicAdd(&cnt[dst[e] >> RB_SHIFT], 1);
    __syncthreads();

    for (int i = threadIdx.x; i < nbuck; i += 1024) {
        const int c = cnt[i];
        base[i] = i * CAP + (c ? atomicAdd(&gcur[i], c) : 0);
        cnt[i] = 0;
    }
    __syncthreads();

    e = e0 + threadIdx.x * 4;
    for (; e + 3 < e1; e += 4096) {
        const int4 d4 = *(const int4*)(dst + e);
        const int4 s4 = *(const int4*)(src + e);
        const float4 w4 = *(const float4*)(ew + e);
        {
            const int b = d4.x >> RB_SHIFT;
            const int p = atomicAdd(&cnt[b], 1);
            edata[(size_t)base[b] + p] = ((u64)__float_as_uint(w4.x) << 32) |
                (u32)s4.x | ((u32)(d4.x & (RB - 1)) << 20);
        }
        {
            const int b = d4.y >> RB_SHIFT;
            const int p = atomicAdd(&cnt[b], 1);
            edata[(size_t)base[b] + p] = ((u64)__float_as_uint(w4.y) << 32) |
                (u32)s4.y | ((u32)(d4.y & (RB - 1)) << 20);
        }
        {
            const int b = d4.z >> RB_SHIFT;
            const int p = atomicAdd(&cnt[b], 1);
            edata[(size_t)base[b] + p] = ((u64)__float_as_uint(w4.z) << 32) |
                (u32)s4.z | ((u32)(d4.z & (RB - 1)) << 20);
        }
        {
            const int b = d4.w >> RB_SHIFT;
            const int p = atomicAdd(&cnt[b], 1);
            edata[(size_t)base[b] + p] = ((u64)__float_as_uint(w4.w) << 32) |
                (u32)s4.w | ((u32)(d4.w & (RB - 1)) << 20);
        }
    }
    for (; e < e1; ++e) {
        const int d = dst[e];
        const int b = d >> RB_SHIFT;
        const int p = atomicAdd(&cnt[b], 1);
        edata[(size_t)base[b] + p] = ((u64)__float_as_uint(ew[e]) << 32) |
            (u32)src[e] | ((u32)(d & (RB - 1)) << 20);
    }
}

// ---------------------------------------------------------------------------
// aggL1: one 1024-thread block per bucket.
//  1) counting-sort edges by local dst into LDS (esh); degree-rank nodes
//  2) 128 groups x 8 lanes; group g = degree rank g, ONE node each.
//     uint4 bf16 gathers (16B/lane -> 8 addresses per edge, was 16).
//  3) barrier; stage relu(acc+b1) as bf16 into reused esh (16KB);
//     barrier; gemm2-style W2 pass (8 thr/node x 2 cols) -> h2b bf16.
// ---------------------------------------------------------------------------
__global__ __launch_bounds__(1024) void aggL1_kernel(
    const u32* __restrict__ h1b, const u64* __restrict__ edata,
    const int* __restrict__ gcnt, const float* __restrict__ b1,
    const float* __restrict__ W2, u32* __restrict__ h2b, int N) {
    __shared__ u64 esh[LDSCAP];          // 22.5 KB sorted edges; reused as bf16 acc staging
    __shared__ float w2s[64 * 16];       // 4 KB
    __shared__ int cnt[RB];
    __shared__ int pref[RB];             // inclusive prefix
    __shared__ int cur[RB];
    __shared__ int dbin[DBINS];
    __shared__ int dcur[DBINS];
    __shared__ int nodeOrder[RB];

    const int tid = threadIdx.x;
    const int b = blockIdx.x;
    const size_t s0 = (size_t)b * CAP;
    const int ecount = min(gcnt[b], LDSCAP);

    w2s[tid] = W2[tid];
    if (tid < RB) cnt[tid] = 0;
    if (tid < DBINS) dbin[tid] = 0;
    __syncthreads();

    // pass 1: per-node counts
    for (int i = tid; i < ecount; i += 1024) {
        const int d = ((u32)edata[s0 + i] >> 20) & (RB - 1);
        atomicAdd(&cnt[d], 1);
    }
    __syncthreads();
    if (tid < RB) pref[tid] = cnt[tid];
    __syncthreads();
    for (int o = 1; o < RB; o <<= 1) {
        int v = 0;
        if (tid < RB && tid >= o) v = pref[tid - o];
        __syncthreads();
        if (tid < RB) pref[tid] += v;
        __syncthreads();
    }
    if (tid < RB) {
        cur[tid] = pref[tid] - cnt[tid];               // exclusive
        atomicAdd(&dbin[min(cnt[tid], DBINS - 1)], 1); // degree histogram
    }
    __syncthreads();
    if (tid < DBINS) dcur[tid] = dbin[tid];
    __syncthreads();
    for (int o = 1; o < DBINS; o <<= 1) {
        int v = 0;
        if (tid < DBINS && tid >= o) v = dcur[tid - o];
        __syncthreads();
        if (tid < DBINS) dcur[tid] += v;
        __syncthreads();
    }
    if (tid < DBINS) dcur[tid] -= dbin[tid];           // exclusive
    __syncthreads();
    if (tid < RB) {
        const int r = atomicAdd(&dcur[min(cnt[tid], DBINS - 1)], 1);
        nodeOrder[r] = tid;
    }
    // pass 2: scatter edges into LDS in node-sorted order
    for (int i = tid; i < ecount; i += 1024) {
        const u64 ed = edata[s0 + i];
        const int d = ((u32)ed >> 20) & (RB - 1);
        const int p = atomicAdd(&cur[d], 1);
        esh[p] = ed;
    }
    __syncthreads();

    // gather: group g (8 lanes) = degree rank g (one node)
    const int g = tid >> 3;
    const int l = tid & 7;               // feats 8l .. 8l+7
    const int ln = nodeOrder[g];
    const int end = pref[ln];
    int i = end - cnt[ln];

    float acc[8];
    {
        const float4 ba = *(const float4*)(b1 + 8 * l);
        const float4 bb = *(const float4*)(b1 + 8 * l + 4);
        acc[0] = ba.x; acc[1] = ba.y; acc[2] = ba.z; acc[3] = ba.w;
        acc[4] = bb.x; acc[5] = bb.y; acc[6] = bb.z; acc[7] = bb.w;
    }
    for (; i + 4 <= end; i += 4) {
        u64 e[4];
        uint4 v[4];
        #pragma unroll
        for (int j = 0; j < 4; ++j) e[j] = esh[i + j];
        #pragma unroll
        for (int j = 0; j < 4; ++j)
            v[j] = *(const uint4*)(h1b + (size_t)((u32)e[j] & 0xFFFFF) * 32 + l * 4);
        #pragma unroll
        for (int j = 0; j < 4; ++j) {
            const float w = __uint_as_float((u32)(e[j] >> 32));
            acc[0] += __uint_as_float(v[j].x << 16) * w;
            acc[1] += __uint_as_float(v[j].x & 0xFFFF0000u) * w;
            acc[2] += __uint_as_float(v[j].y << 16) * w;
            acc[3] += __uint_as_float(v[j].y & 0xFFFF0000u) * w;
            acc[4] += __uint_as_float(v[j].z << 16) * w;
            acc[5] += __uint_as_float(v[j].z & 0xFFFF0000u) * w;
            acc[6] += __uint_as_float(v[j].w << 16) * w;
            acc[7] += __uint_as_float(v[j].w & 0xFFFF0000u) * w;
        }
    }
    for (; i < end; ++i) {
        const u64 e0 = esh[i];
        const float w0 = __uint_as_float((u32)(e0 >> 32));
        const uint4 v0 = *(const uint4*)(h1b + (size_t)((u32)e0 & 0xFFFFF) * 32 + l * 4);
        acc[0] += __uint_as_float(v0.x << 16) * w0;
        acc[1] += __uint_as_float(v0.x & 0xFFFF0000u) * w0;
        acc[2] += __uint_as_float(v0.y << 16) * w0;
        acc[3] += __uint_as_float(v0.y & 0xFFFF0000u) * w0;
        acc[4] += __uint_as_float(v0.z << 16) * w0;
        acc[5] += __uint_as_float(v0.z & 0xFFFF0000u) * w0;
        acc[6] += __uint_as_float(v0.w << 16) * w0;
        acc[7] += __uint_as_float(v0.w & 0xFFFF0000u) * w0;
    }

    // relu + pack to bf16
    u32 pk[4];
    #pragma unroll
    for (int j = 0; j < 4; ++j)
        pk[j] = pack2bf16(fmaxf(acc[2 * j], 0.f), fmaxf(acc[2 * j + 1], 0.f));

    __syncthreads();                     // all esh reads done; safe to reuse
    // stage: slot g holds 64 feats as 32 u32 (2 bf16 each)
    u32* stg = (u32*)esh;                // 128 * 32 * 4B = 16 KB
    #pragma unroll
    for (int j = 0; j < 4; ++j) stg[g * 32 + l * 4 + j] = pk[j];
    __syncthreads();

    // W2 pass: slot s = tid>>3, col pair c = tid&7 (cols 2c, 2c+1)
    const int s = tid >> 3;
    const int c = tid & 7;
    float o0 = 0.f, o1 = 0.f;
    #pragma unroll 8
    for (int w = 0; w < 32; ++w) {       // feats 2w, 2w+1
        const u32 pw = stg[s * 32 + w];
        const float f0 = __uint_as_float(pw << 16);
        const float f1 = __uint_as_float(pw & 0xFFFF0000u);
        o0 += f0 * w2s[(2 * w) * 16 + 2 * c] + f1 * w2s[(2 * w + 1) * 16 + 2 * c];
        o1 += f0 * w2s[(2 * w) * 16 + 2 * c + 1] + f1 * w2s[(2 * w + 1) * 16 + 2 * c + 1];
    }
    const int gn = b * RB + nodeOrder[s];
    if (gn < N) h2b[(size_t)gn * 8 + c] = pack2bf16(o0, o1);
}

// ---------------------------------------------------------------------------
// aggL2: one 512-thread block per bucket.
//  in-LDS sort + degree rank (512-thr preamble, R9-measured); then
//  128 groups x 2 lanes (tid<256): lane = 16B half of the 32B h2b row ->
//  2 addresses per edge (was 4). Register acc, unroll 4, float4x2 writeout.
// ---------------------------------------------------------------------------
__global__ __launch_bounds__(512) void aggL2_kernel(
    const u32* __restrict__ h2b, const u64* __restrict__ edata,
    const int* __restrict__ gcnt, const float* __restrict__ b2,
    float* __restrict__ out, int N) {
    __shared__ u64 esh[LDSCAP];          // 22.5 KB sorted edges
    __shared__ int cnt[RB];
    __shared__ int pref[RB];
    __shared__ int cur[RB];
    __shared__ int dbin[DBINS];
    __shared__ int dcur[DBINS];
    __shared__ int nodeOrder[RB];

    const int tid = threadIdx.x;
    const int b = blockIdx.x;
    const size_t s0 = (size_t)b * CAP;
    const int ecount = min(gcnt[b], LDSCAP);

    if (tid < RB) cnt[tid] = 0;
    if (tid < DBINS) dbin[tid] = 0;
    __syncthreads();

    for (int i = tid; i < ecount; i += 512) {
        const int d = ((u32)edata[s0 + i] >> 20) & (RB - 1);
        atomicAdd(&cnt[d], 1);
    }
    __syncthreads();
    if (tid < RB) pref[tid] = cnt[tid];
    __syncthreads();
    for (int o = 1; o < RB; o <<= 1) {
        int v = 0;
        if (tid < RB && tid >= o) v = pref[tid - o];
        __syncthreads();
        if (tid < RB) pref[tid] += v;
        __syncthreads();
    }
    if (tid < RB) {
        cur[tid] = pref[tid] - cnt[tid];
        atomicAdd(&dbin[min(cnt[tid], DBINS - 1)], 1);
    }
    __syncthreads();
    if (tid < DBINS) dcur[tid] = dbin[tid];
    __syncthreads();
    for (int o = 1; o < DBINS; o <<= 1) {
        int v = 0;
        if (tid < DBINS && tid >= o) v = dcur[tid - o];
        __syncthreads();
        if (tid < DBINS) dcur[tid] += v;
        __syncthreads();
    }
    if (tid < DBINS) dcur[tid] -= dbin[tid];
    __syncthreads();
    if (tid < RB) {
        const int r = atomicAdd(&dcur[min(cnt[tid], DBINS - 1)], 1);
        nodeOrder[r] = tid;
    }
    __syncthreads();
    for (int i = tid; i < ecount; i += 512) {
        const u64 ed = edata[s0 + i];
        const int d = ((u32)ed >> 20) & (RB - 1);
        const int p = atomicAdd(&cur[d], 1);
        esh[p] = ed;
    }
    __syncthreads();

    if (tid >= 256) return;             // aggregation uses 128 x 2 lanes
    const int g = tid >> 1;             // degree rank (one node)
    const int l = tid & 1;              // feats 8l .. 8l+7 (16B half)
    const int ln = nodeOrder[g];
    const int gn = b * RB + ln;
    const int end = pref[ln];
    int i = end - cnt[ln];

    float acc[8];
    {
        const float4 ba = *(const float4*)(b2 + 8 * l);
        const float4 bb = *(const float4*)(b2 + 8 * l + 4);
        acc[0] = ba.x; acc[1] = ba.y; acc[2] = ba.z; acc[3] = ba.w;
        acc[4] = bb.x; acc[5] = bb.y; acc[6] = bb.z; acc[7] = bb.w;
    }
    for (; i + 4 <= end; i += 4) {
        u64 e[4];
        uint4 v[4];
        #pragma unroll
        for (int j = 0; j < 4; ++j) e[j] = esh[i + j];
        #pragma unroll
        for (int j = 0; j < 4; ++j)
            v[j] = *(const uint4*)(h2b + (size_t)((u32)e[j] & 0xFFFFF) * 8 + l * 4);
        #pragma unroll
        for (int j = 0; j < 4; ++j) {
            const float w = __uint_as_float((u32)(e[j] >> 32));
            acc[0] += __uint_as_float(v[j].x << 16) * w;
            acc[1] += __uint_as_float(v[j].x & 0xFFFF0000u) * w;
            acc[2] += __uint_as_float(v[j].y << 16) * w;
            acc[3] += __uint_as_float(v[j].y & 0xFFFF0000u) * w;
            acc[4] += __uint_as_float(v[j].z << 16) * w;
            acc[5] += __uint_as_float(v[j].z & 0xFFFF0000u) * w;
            acc[6] += __uint_as_float(v[j].w << 16) * w;
            acc[7] += __uint_as_float(v[j].w & 0xFFFF0000u) * w;
        }
    }
    for (; i < end; ++i) {
        const u64 e0 = esh[i];
        const float w0 = __uint_as_float((u32)(e0 >> 32));
        const uint4 v0 = *(const uint4*)(h2b + (size_t)((u32)e0 & 0xFFFFF) * 8 + l * 4);
        acc[0] += __uint_as_float(v0.x << 16) * w0;
        acc[1] += __uint_as_float(v0.x & 0xFFFF0000u) * w0;
        acc[2] += __uint_as_float(v0.y << 16) * w0;
        acc[3] += __uint_as_float(v0.y & 0xFFFF0000u) * w0;
        acc[4] += __uint_as_float(v0.z << 16) * w0;
        acc[5] += __uint_as_float(v0.z & 0xFFFF0000u) * w0;
        acc[6] += __uint_as_float(v0.w << 16) * w0;
        acc[7] += __uint_as_float(v0.w & 0xFFFF0000u) * w0;
    }
    if (gn < N) {
        float* p = out + (size_t)gn * F_OUT + 8 * l;
        *(float4*)(p + 0) = make_float4(acc[0], acc[1], acc[2], acc[3]);
        *(float4*)(p + 4) = make_float4(acc[4], acc[5], acc[6], acc[7]);
    }
}

extern "C" void kernel_launch(void* const* d_in, const int* in_sizes, int n_in,
                              void* d_out, int out_size, void* d_ws, size_t ws_size,
                              hipStream_t stream) {
    const float* x   = (const float*)d_in[0];
    const int*   src = (const int*)d_in[1];
    const int*   dst = (const int*)d_in[2];
    const float* ew  = (const float*)d_in[3];
    const float* W1  = (const float*)d_in[4];
    const float* b1  = (const float*)d_in[5];
    const float* W2  = (const float*)d_in[6];
    const float* b2  = (const float*)d_in[7];
    float* out = (float*)d_out;

    const int N = in_sizes[0] / F_IN;            // 100000
    const int E = in_sizes[1];                   // 1600000
    const int nbuck = (N + RB - 1) >> RB_SHIFT;  // 782

    char* base = (char*)d_ws;
    auto align256 = [](size_t v) { return (v + 255) & ~(size_t)255; };
    size_t oH1  = 0;
    size_t oED1 = align256(oH1  + (size_t)N * 32 * 4);       // h1b bf16 12.8MB
    size_t oH2B = align256(oED1 + (size_t)nbuck * CAP * 8);  // edata1 19.2MB
    size_t oCUR = align256(oH2B + (size_t)N * 8 * 4);        // h2b bf16 3.2MB
    (void)ws_size;

    u32*   h1b    = (u32*)(base + oH1);
    u64*   edata1 = (u64*)(base + oED1);
    u32*   h2b    = (u32*)(base + oH2B);
    int*   gcur   = (int*)(base + oCUR);

    // ---- preprocessing: CAP-strided bucket fill (counts end up in gcur)
    hipMemsetAsync(gcur, 0, (size_t)nbuck * 4, stream);
    fill_kernel<<<256, 1024, 0, stream>>>(src, dst, ew, gcur, edata1, E, nbuck);

    // ---- layer 1 transform
    gemm1_kernel<<<(N + 63) / 64, 256, 0, stream>>>(x, W1, h1b, N);
    // ---- layer-1 aggregate + relu + W2 (in-LDS sort, uint4 gathers) -> h2b
    aggL1_kernel<<<nbuck, 1024, 0, stream>>>(h1b, edata1, gcur, b1, W2, h2b, N);
    // ---- layer-2 aggregate + bias (in-LDS sort, 2-lane uint4 gathers)
    aggL2_kernel<<<nbuck, 512, 0, stream>>>(h2b, edata1, gcur, b2, out, N);
}

// Round 13
// 105.593 us; speedup vs baseline: 1.3426x; 1.1568x over previous
//
#include <hip/hip_runtime.h>

#define F_IN 128
#define F_H 64
#define F_OUT 16
#define RB 128           // nodes per bucket
#define RB_SHIFT 7       // bucket = dst >> 7
#define DBINS 64         // degree bins for bucket-local degree ranking
#define CAP 3072         // global bucket capacity (mean 2047, sigma 45)
#define LDSCAP 2816      // LDS sorted-edge capacity (mean + 17 sigma)
#define XSTR 136         // bf16 LDS row stride (mult of 8 -> 16B-aligned b128; 2-way banks)

typedef unsigned long long u64;
typedef unsigned int u32;
typedef unsigned short u16;
typedef __attribute__((ext_vector_type(8))) short short8;
typedef __attribute__((ext_vector_type(4))) float floatx4;

__device__ __forceinline__ u32 pack2bf16(float a, float b) {
    u32 ua = (__float_as_uint(a) + 0x8000u) >> 16;
    u32 ub = (__float_as_uint(b) + 0x8000u) & 0xFFFF0000u;
    return ua | ub;
}
__device__ __forceinline__ u16 bf16r(float a) {
    return (u16)((__float_as_uint(a) + 0x8000u) >> 16);
}

// ---------------------------------------------------------------------------
// GEMM1 (MFMA bf16): h1[N,64](bf16 u32-pair rows) = x[N,128] @ W1[128,64]
// 256 thr = 4 waves; tile 64 nodes x 64 feats; K=128 in 4 steps of 32.
// ---------------------------------------------------------------------------
__global__ __launch_bounds__(256) void gemm1_kernel(
    const float* __restrict__ x, const float* __restrict__ W,
    u32* __restrict__ h1b, int N) {
    __shared__ u16 sh[2 * 64 * XSTR];    // 34.8 KB: xls | w1t; reused as f32 stage
    u16* xls = sh;                       // [64][XSTR]  x tile bf16 [node][k]
    u16* w1t = sh + 64 * XSTR;           // [64][XSTR]  W1^T bf16 [col][k]
    float* stage = (float*)sh;           // [64][65] f32 C staging (epilogue)

    const int tid = threadIdx.x;
    const int n0 = blockIdx.x * 64;

    // load x tile -> bf16 LDS
    {
        const int c4 = (tid & 31) * 4;   // k offset 0..124
        const int r0 = tid >> 5;         // 0..7
        #pragma unroll
        for (int r = 0; r < 8; ++r) {
            const int row = r0 + r * 8;
            int n = n0 + row;
            if (n >= N) n = N - 1;
            const float4 v = *(const float4*)(x + (size_t)n * F_IN + c4);
            u16* p = &xls[row * XSTR + c4];
            p[0] = bf16r(v.x); p[1] = bf16r(v.y);
            p[2] = bf16r(v.z); p[3] = bf16r(v.w);
        }
    }
    // load W1 transposed -> bf16 LDS: w1t[col][k]
    {
        const int k0 = tid >> 4;         // 0..15
        const int c4 = (tid & 15) * 4;   // col 0..60
        #pragma unroll
        for (int r = 0; r < 8; ++r) {
            const int k = k0 + r * 16;
            const float4 v = *(const float4*)(W + (size_t)k * F_H + c4);
            w1t[(c4 + 0) * XSTR + k] = bf16r(v.x);
            w1t[(c4 + 1) * XSTR + k] = bf16r(v.y);
            w1t[(c4 + 2) * XSTR + k] = bf16r(v.z);
            w1t[(c4 + 3) * XSTR + k] = bf16r(v.w);
        }
    }
    __syncthreads();

    const int wv = tid >> 6;             // wave 0..3 -> nodes 16wv..16wv+15
    const int l = tid & 63;
    const int lr = l & 15;               // A row / B col within 16-tile
    const int lk = (l >> 4) * 8;         // k sub-base within 32-step

    floatx4 acc[4] = {{0.f, 0.f, 0.f, 0.f}, {0.f, 0.f, 0.f, 0.f},
                      {0.f, 0.f, 0.f, 0.f}, {0.f, 0.f, 0.f, 0.f}};
    #pragma unroll
    for (int ks = 0; ks < 4; ++ks) {
        const short8 a = *(const short8*)&xls[(wv * 16 + lr) * XSTR + ks * 32 + lk];
        #pragma unroll
        for (int c = 0; c < 4; ++c) {
            const short8 bfr = *(const short8*)&w1t[(c * 16 + lr) * XSTR + ks * 32 + lk];
            acc[c] = __builtin_amdgcn_mfma_f32_16x16x32_bf16(a, bfr, acc[c], 0, 0, 0);
        }
    }
    __syncthreads();                     // xls/w1t reads done; reuse as stage

    // C layout (verified): col = lane&15, row = (lane>>4)*4 + reg
    #pragma unroll
    for (int c = 0; c < 4; ++c) {
        #pragma unroll
        for (int r = 0; r < 4; ++r) {
            const int row = wv * 16 + (l >> 4) * 4 + r;
            stage[row * 65 + c * 16 + lr] = acc[c][r];
        }
    }
    __syncthreads();

    // pack f32 pairs -> bf16 u32, coalesced store (2048 u32 per block)
    #pragma unroll
    for (int t = 0; t < 8; ++t) {
        const int idx = t * 256 + tid;   // 0..2047
        const int row = idx >> 5, j = idx & 31;
        const int n = n0 + row;
        if (n < N) {
            const float f0 = stage[row * 65 + 2 * j];
            const float f1 = stage[row * 65 + 2 * j + 1];
            h1b[(size_t)n * 32 + j] = pack2bf16(f0, f1);
        }
    }
}

// ---------------------------------------------------------------------------
// fill: block-local counting sort into CAP-strided bucket-grouped edata1
// entry: [63:32]=weight f32 bits, [26:20]=dst&127, [19:0]=src
// gcur[b] (zeroed before) ends as the bucket's edge count.
// 128 blocks -> ~16-edge (128B) runs per bucket per block: less write amp.
// ---------------------------------------------------------------------------
__global__ __launch_bounds__(1024) void fill_kernel(
    const int* __restrict__ src, const int* __restrict__ dst,
    const float* __restrict__ ew, int* __restrict__ gcur,
    u64* __restrict__ edata, int E, int nbuck) {
    __shared__ int cnt[800];
    __shared__ int base[800];
    int chunk = (E + gridDim.x - 1) / gridDim.x;
    chunk = (chunk + 3) & ~3;
    const int e0 = blockIdx.x * chunk;
    const int e1 = min(e0 + chunk, E);

    for (int i = threadIdx.x; i < nbuck; i += 1024) cnt[i] = 0;
    __syncthreads();

    int e = e0 + threadIdx.x * 4;
    for (; e + 3 < e1; e += 4096) {
        const int4 d4 = *(const int4*)(dst + e);
        atomicAdd(&cnt[d4.x >> RB_SHIFT], 1);
        atomicAdd(&cnt[d4.y >> RB_SHIFT], 1);
        atomicAdd(&cnt[d4.z >> RB_SHIFT], 1);
        atomicAdd(&cnt[d4.w >> RB_SHIFT], 1);
    }
    for (; e < e1; ++e) atomicAdd(&cnt[dst[e] >> RB_SHIFT], 1);
    __syncthreads();

    for (int i = threadIdx.x; i < nbuck; i += 1024) {
        const int c = cnt[i];
        base[i] = i * CAP + (c ? atomicAdd(&gcur[i], c) : 0);
        cnt[i] = 0;
    }
    __syncthreads();

    e = e0 + threadIdx.x * 4;
    for (; e + 3 < e1; e += 4096) {
        const int4 d4 = *(const int4*)(dst + e);
        const int4 s4 = *(const int4*)(src + e);
        const float4 w4 = *(const float4*)(ew + e);
        {
            const int b = d4.x >> RB_SHIFT;
            const int p = atomicAdd(&cnt[b], 1);
            edata[(size_t)base[b] + p] = ((u64)__float_as_uint(w4.x) << 32) |
                (u32)s4.x | ((u32)(d4.x & (RB - 1)) << 20);
        }
        {
            const int b = d4.y >> RB_SHIFT;
            const int p = atomicAdd(&cnt[b], 1);
            edata[(size_t)base[b] + p] = ((u64)__float_as_uint(w4.y) << 32) |
                (u32)s4.y | ((u32)(d4.y & (RB - 1)) << 20);
        }
        {
            const int b = d4.z >> RB_SHIFT;
            const int p = atomicAdd(&cnt[b], 1);
            edata[(size_t)base[b] + p] = ((u64)__float_as_uint(w4.z) << 32) |
                (u32)s4.z | ((u32)(d4.z & (RB - 1)) << 20);
        }
        {
            const int b = d4.w >> RB_SHIFT;
            const int p = atomicAdd(&cnt[b], 1);
            edata[(size_t)base[b] + p] = ((u64)__float_as_uint(w4.w) << 32) |
                (u32)s4.w | ((u32)(d4.w & (RB - 1)) << 20);
        }
    }
    for (; e < e1; ++e) {
        const int d = dst[e];
        const int b = d >> RB_SHIFT;
        const int p = atomicAdd(&cnt[b], 1);
        edata[(size_t)base[b] + p] = ((u64)__float_as_uint(ew[e]) << 32) |
            (u32)src[e] | ((u32)(d & (RB - 1)) << 20);
    }
}

// ---------------------------------------------------------------------------
// aggL1: one 1024-thread block per bucket. (unchanged from R12)
// ---------------------------------------------------------------------------
__global__ __launch_bounds__(1024) void aggL1_kernel(
    const u32* __restrict__ h1b, const u64* __restrict__ edata,
    const int* __restrict__ gcnt, const float* __restrict__ b1,
    const float* __restrict__ W2, u32* __restrict__ h2b, int N) {
    __shared__ u64 esh[LDSCAP];          // sorted edges; reused as bf16 staging
    __shared__ float w2s[64 * 16];
    __shared__ int cnt[RB];
    __shared__ int pref[RB];
    __shared__ int cur[RB];
    __shared__ int dbin[DBINS];
    __shared__ int dcur[DBINS];
    __shared__ int nodeOrder[RB];

    const int tid = threadIdx.x;
    const int b = blockIdx.x;
    const size_t s0 = (size_t)b * CAP;
    const int ecount = min(gcnt[b], LDSCAP);

    w2s[tid] = W2[tid];
    if (tid < RB) cnt[tid] = 0;
    if (tid < DBINS) dbin[tid] = 0;
    __syncthreads();

    for (int i = tid; i < ecount; i += 1024) {
        const int d = ((u32)edata[s0 + i] >> 20) & (RB - 1);
        atomicAdd(&cnt[d], 1);
    }
    __syncthreads();
    if (tid < RB) pref[tid] = cnt[tid];
    __syncthreads();
    for (int o = 1; o < RB; o <<= 1) {
        int v = 0;
        if (tid < RB && tid >= o) v = pref[tid - o];
        __syncthreads();
        if (tid < RB) pref[tid] += v;
        __syncthreads();
    }
    if (tid < RB) {
        cur[tid] = pref[tid] - cnt[tid];
        atomicAdd(&dbin[min(cnt[tid], DBINS - 1)], 1);
    }
    __syncthreads();
    if (tid < DBINS) dcur[tid] = dbin[tid];
    __syncthreads();
    for (int o = 1; o < DBINS; o <<= 1) {
        int v = 0;
        if (tid < DBINS && tid >= o) v = dcur[tid - o];
        __syncthreads();
        if (tid < DBINS) dcur[tid] += v;
        __syncthreads();
    }
    if (tid < DBINS) dcur[tid] -= dbin[tid];
    __syncthreads();
    if (tid < RB) {
        const int r = atomicAdd(&dcur[min(cnt[tid], DBINS - 1)], 1);
        nodeOrder[r] = tid;
    }
    for (int i = tid; i < ecount; i += 1024) {
        const u64 ed = edata[s0 + i];
        const int d = ((u32)ed >> 20) & (RB - 1);
        const int p = atomicAdd(&cur[d], 1);
        esh[p] = ed;
    }
    __syncthreads();

    const int g = tid >> 3;
    const int l = tid & 7;
    const int ln = nodeOrder[g];
    const int end = pref[ln];
    int i = end - cnt[ln];

    float acc[8];
    {
        const float4 ba = *(const float4*)(b1 + 8 * l);
        const float4 bb = *(const float4*)(b1 + 8 * l + 4);
        acc[0] = ba.x; acc[1] = ba.y; acc[2] = ba.z; acc[3] = ba.w;
        acc[4] = bb.x; acc[5] = bb.y; acc[6] = bb.z; acc[7] = bb.w;
    }
    for (; i + 4 <= end; i += 4) {
        u64 e[4];
        uint4 v[4];
        #pragma unroll
        for (int j = 0; j < 4; ++j) e[j] = esh[i + j];
        #pragma unroll
        for (int j = 0; j < 4; ++j)
            v[j] = *(const uint4*)(h1b + (size_t)((u32)e[j] & 0xFFFFF) * 32 + l * 4);
        #pragma unroll
        for (int j = 0; j < 4; ++j) {
            const float w = __uint_as_float((u32)(e[j] >> 32));
            acc[0] += __uint_as_float(v[j].x << 16) * w;
            acc[1] += __uint_as_float(v[j].x & 0xFFFF0000u) * w;
            acc[2] += __uint_as_float(v[j].y << 16) * w;
            acc[3] += __uint_as_float(v[j].y & 0xFFFF0000u) * w;
            acc[4] += __uint_as_float(v[j].z << 16) * w;
            acc[5] += __uint_as_float(v[j].z & 0xFFFF0000u) * w;
            acc[6] += __uint_as_float(v[j].w << 16) * w;
            acc[7] += __uint_as_float(v[j].w & 0xFFFF0000u) * w;
        }
    }
    for (; i < end; ++i) {
        const u64 e0 = esh[i];
        const float w0 = __uint_as_float((u32)(e0 >> 32));
        const uint4 v0 = *(const uint4*)(h1b + (size_t)((u32)e0 & 0xFFFFF) * 32 + l * 4);
        acc[0] += __uint_as_float(v0.x << 16) * w0;
        acc[1] += __uint_as_float(v0.x & 0xFFFF0000u) * w0;
        acc[2] += __uint_as_float(v0.y << 16) * w0;
        acc[3] += __uint_as_float(v0.y & 0xFFFF0000u) * w0;
        acc[4] += __uint_as_float(v0.z << 16) * w0;
        acc[5] += __uint_as_float(v0.z & 0xFFFF0000u) * w0;
        acc[6] += __uint_as_float(v0.w << 16) * w0;
        acc[7] += __uint_as_float(v0.w & 0xFFFF0000u) * w0;
    }

    u32 pk[4];
    #pragma unroll
    for (int j = 0; j < 4; ++j)
        pk[j] = pack2bf16(fmaxf(acc[2 * j], 0.f), fmaxf(acc[2 * j + 1], 0.f));

    __syncthreads();
    u32* stg = (u32*)esh;
    #pragma unroll
    for (int j = 0; j < 4; ++j) stg[g * 32 + l * 4 + j] = pk[j];
    __syncthreads();

    const int s = tid >> 3;
    const int c = tid & 7;
    float o0 = 0.f, o1 = 0.f;
    #pragma unroll 8
    for (int w = 0; w < 32; ++w) {
        const u32 pw = stg[s * 32 + w];
        const float f0 = __uint_as_float(pw << 16);
        const float f1 = __uint_as_float(pw & 0xFFFF0000u);
        o0 += f0 * w2s[(2 * w) * 16 + 2 * c] + f1 * w2s[(2 * w + 1) * 16 + 2 * c];
        o1 += f0 * w2s[(2 * w) * 16 + 2 * c + 1] + f1 * w2s[(2 * w + 1) * 16 + 2 * c + 1];
    }
    const int gn = b * RB + nodeOrder[s];
    if (gn < N) h2b[(size_t)gn * 8 + c] = pack2bf16(o0, o1);
}

// ---------------------------------------------------------------------------
// aggL2: one 512-thread block per bucket. (unchanged from R12)
// ---------------------------------------------------------------------------
__global__ __launch_bounds__(512) void aggL2_kernel(
    const u32* __restrict__ h2b, const u64* __restrict__ edata,
    const int* __restrict__ gcnt, const float* __restrict__ b2,
    float* __restrict__ out, int N) {
    __shared__ u64 esh[LDSCAP];
    __shared__ int cnt[RB];
    __shared__ int pref[RB];
    __shared__ int cur[RB];
    __shared__ int dbin[DBINS];
    __shared__ int dcur[DBINS];
    __shared__ int nodeOrder[RB];

    const int tid = threadIdx.x;
    const int b = blockIdx.x;
    const size_t s0 = (size_t)b * CAP;
    const int ecount = min(gcnt[b], LDSCAP);

    if (tid < RB) cnt[tid] = 0;
    if (tid < DBINS) dbin[tid] = 0;
    __syncthreads();

    for (int i = tid; i < ecount; i += 512) {
        const int d = ((u32)edata[s0 + i] >> 20) & (RB - 1);
        atomicAdd(&cnt[d], 1);
    }
    __syncthreads();
    if (tid < RB) pref[tid] = cnt[tid];
    __syncthreads();
    for (int o = 1; o < RB; o <<= 1) {
        int v = 0;
        if (tid < RB && tid >= o) v = pref[tid - o];
        __syncthreads();
        if (tid < RB) pref[tid] += v;
        __syncthreads();
    }
    if (tid < RB) {
        cur[tid] = pref[tid] - cnt[tid];
        atomicAdd(&dbin[min(cnt[tid], DBINS - 1)], 1);
    }
    __syncthreads();
    if (tid < DBINS) dcur[tid] = dbin[tid];
    __syncthreads();
    for (int o = 1; o < DBINS; o <<= 1) {
        int v = 0;
        if (tid < DBINS && tid >= o) v = dcur[tid - o];
        __syncthreads();
        if (tid < DBINS) dcur[tid] += v;
        __syncthreads();
    }
    if (tid < DBINS) dcur[tid] -= dbin[tid];
    __syncthreads();
    if (tid < RB) {
        const int r = atomicAdd(&dcur[min(cnt[tid], DBINS - 1)], 1);
        nodeOrder[r] = tid;
    }
    __syncthreads();
    for (int i = tid; i < ecount; i += 512) {
        const u64 ed = edata[s0 + i];
        const int d = ((u32)ed >> 20) & (RB - 1);
        const int p = atomicAdd(&cur[d], 1);
        esh[p] = ed;
    }
    __syncthreads();

    if (tid >= 256) return;
    const int g = tid >> 1;
    const int l = tid & 1;
    const int ln = nodeOrder[g];
    const int gn = b * RB + ln;
    const int end = pref[ln];
    int i = end - cnt[ln];

    float acc[8];
    {
        const float4 ba = *(const float4*)(b2 + 8 * l);
        const float4 bb = *(const float4*)(b2 + 8 * l + 4);
        acc[0] = ba.x; acc[1] = ba.y; acc[2] = ba.z; acc[3] = ba.w;
        acc[4] = bb.x; acc[5] = bb.y; acc[6] = bb.z; acc[7] = bb.w;
    }
    for (; i + 4 <= end; i += 4) {
        u64 e[4];
        uint4 v[4];
        #pragma unroll
        for (int j = 0; j < 4; ++j) e[j] = esh[i + j];
        #pragma unroll
        for (int j = 0; j < 4; ++j)
            v[j] = *(const uint4*)(h2b + (size_t)((u32)e[j] & 0xFFFFF) * 8 + l * 4);
        #pragma unroll
        for (int j = 0; j < 4; ++j) {
            const float w = __uint_as_float((u32)(e[j] >> 32));
            acc[0] += __uint_as_float(v[j].x << 16) * w;
            acc[1] += __uint_as_float(v[j].x & 0xFFFF0000u) * w;
            acc[2] += __uint_as_float(v[j].y << 16) * w;
            acc[3] += __uint_as_float(v[j].y & 0xFFFF0000u) * w;
            acc[4] += __uint_as_float(v[j].z << 16) * w;
            acc[5] += __uint_as_float(v[j].z & 0xFFFF0000u) * w;
            acc[6] += __uint_as_float(v[j].w << 16) * w;
            acc[7] += __uint_as_float(v[j].w & 0xFFFF0000u) * w;
        }
    }
    for (; i < end; ++i) {
        const u64 e0 = esh[i];
        const float w0 = __uint_as_float((u32)(e0 >> 32));
        const uint4 v0 = *(const uint4*)(h2b + (size_t)((u32)e0 & 0xFFFFF) * 8 + l * 4);
        acc[0] += __uint_as_float(v0.x << 16) * w0;
        acc[1] += __uint_as_float(v0.x & 0xFFFF0000u) * w0;
        acc[2] += __uint_as_float(v0.y << 16) * w0;
        acc[3] += __uint_as_float(v0.y & 0xFFFF0000u) * w0;
        acc[4] += __uint_as_float(v0.z << 16) * w0;
        acc[5] += __uint_as_float(v0.z & 0xFFFF0000u) * w0;
        acc[6] += __uint_as_float(v0.w << 16) * w0;
        acc[7] += __uint_as_float(v0.w & 0xFFFF0000u) * w0;
    }
    if (gn < N) {
        float* p = out + (size_t)gn * F_OUT + 8 * l;
        *(float4*)(p + 0) = make_float4(acc[0], acc[1], acc[2], acc[3]);
        *(float4*)(p + 4) = make_float4(acc[4], acc[5], acc[6], acc[7]);
    }
}

extern "C" void kernel_launch(void* const* d_in, const int* in_sizes, int n_in,
                              void* d_out, int out_size, void* d_ws, size_t ws_size,
                              hipStream_t stream) {
    const float* x   = (const float*)d_in[0];
    const int*   src = (const int*)d_in[1];
    const int*   dst = (const int*)d_in[2];
    const float* ew  = (const float*)d_in[3];
    const float* W1  = (const float*)d_in[4];
    const float* b1  = (const float*)d_in[5];
    const float* W2  = (const float*)d_in[6];
    const float* b2  = (const float*)d_in[7];
    float* out = (float*)d_out;

    const int N = in_sizes[0] / F_IN;            // 100000
    const int E = in_sizes[1];                   // 1600000
    const int nbuck = (N + RB - 1) >> RB_SHIFT;  // 782

    char* base = (char*)d_ws;
    auto align256 = [](size_t v) { return (v + 255) & ~(size_t)255; };
    size_t oH1  = 0;
    size_t oED1 = align256(oH1  + (size_t)N * 32 * 4);       // h1b bf16 12.8MB
    size_t oH2B = align256(oED1 + (size_t)nbuck * CAP * 8);  // edata1 19.2MB
    size_t oCUR = align256(oH2B + (size_t)N * 8 * 4);        // h2b bf16 3.2MB
    (void)ws_size;

    u32*   h1b    = (u32*)(base + oH1);
    u64*   edata1 = (u64*)(base + oED1);
    u32*   h2b    = (u32*)(base + oH2B);
    int*   gcur   = (int*)(base + oCUR);

    // ---- preprocessing: CAP-strided bucket fill (counts end up in gcur)
    hipMemsetAsync(gcur, 0, (size_t)nbuck * 4, stream);
    fill_kernel<<<128, 1024, 0, stream>>>(src, dst, ew, gcur, edata1, E, nbuck);

    // ---- layer 1 transform (MFMA bf16)
    gemm1_kernel<<<(N + 63) / 64, 256, 0, stream>>>(x, W1, h1b, N);
    // ---- layer-1 aggregate + relu + W2 (in-LDS sort, uint4 gathers) -> h2b
    aggL1_kernel<<<nbuck, 1024, 0, stream>>>(h1b, edata1, gcur, b1, W2, h2b, N);
    // ---- layer-2 aggregate + bias (in-LDS sort, 2-lane uint4 gathers)
    aggL2_kernel<<<nbuck, 512, 0, stream>>>(h2b, edata1, gcur, b2, out, N);
}